// Round 1
// baseline (3428.732 us; speedup 1.0000x reference)
//
#include <hip/hip_runtime.h>
#include <math.h>

#define TT 2048
#define DD 1024
#define HH 16
#define DKK 64
#define BBATCH 4
#define NN 8192  // BBATCH*TT

// ---------------------------------------------------------------------------
// GEMM: C = X @ W + bias.  X: NN x DD row-major f32, W: DD x DD row-major.
// 128x128 tile, 256 threads, 8x8 micro-tile, K-step 16.
// MODE 0: scatter to (B,H,T,DK) layout for attention.  MODE 1: row-major.
// ---------------------------------------------------------------------------
template <int MODE>
__global__ __launch_bounds__(256) void gemm_bias_f32(
    const float* __restrict__ X, const float* __restrict__ W,
    const float* __restrict__ bias, float* __restrict__ C) {
  __shared__ float Xs[128][20];   // pad 16->20: conflict-free a-reads, f4-aligned
  __shared__ float Ws[16][128];

  const int tid = threadIdx.x;
  const int tx = tid & 15, ty = tid >> 4;
  const int rb = blockIdx.x * 128, cb = blockIdx.y * 128;

  float acc[8][8];
#pragma unroll
  for (int i = 0; i < 8; ++i)
#pragma unroll
    for (int j = 0; j < 8; ++j) acc[i][j] = 0.f;

  const int xr = tid >> 1, xc = (tid & 1) * 8;   // X tile loader: 128x16
  const int wr = tid >> 4, wc = (tid & 15) * 8;  // W tile loader: 16x128

  for (int k0 = 0; k0 < DD; k0 += 16) {
    __syncthreads();
    const float4* xg =
        reinterpret_cast<const float4*>(&X[(size_t)(rb + xr) * DD + k0 + xc]);
    float4 a0 = xg[0], a1 = xg[1];
    *reinterpret_cast<float4*>(&Xs[xr][xc]) = a0;
    *reinterpret_cast<float4*>(&Xs[xr][xc + 4]) = a1;
    const float4* wg =
        reinterpret_cast<const float4*>(&W[(size_t)(k0 + wr) * DD + cb + wc]);
    float4 b0 = wg[0], b1 = wg[1];
    *reinterpret_cast<float4*>(&Ws[wr][wc]) = b0;
    *reinterpret_cast<float4*>(&Ws[wr][wc + 4]) = b1;
    __syncthreads();
#pragma unroll
    for (int kk = 0; kk < 16; ++kk) {
      float a[8], b[8];
#pragma unroll
      for (int i = 0; i < 8; ++i) a[i] = Xs[ty + 16 * i][kk];
#pragma unroll
      for (int j = 0; j < 8; ++j) b[j] = Ws[kk][tx + 16 * j];
#pragma unroll
      for (int i = 0; i < 8; ++i)
#pragma unroll
        for (int j = 0; j < 8; ++j) acc[i][j] = fmaf(a[i], b[j], acc[i][j]);
    }
  }

  float bv[8];
#pragma unroll
  for (int j = 0; j < 8; ++j) bv[j] = bias[cb + tx + 16 * j];

#pragma unroll
  for (int i = 0; i < 8; ++i) {
    const int r = rb + ty + 16 * i;
#pragma unroll
    for (int j = 0; j < 8; ++j) {
      const int c = cb + tx + 16 * j;
      const float v = acc[i][j] + bv[j];
      if (MODE == 0) {
        const int b = r >> 11, t = r & 2047, h = c >> 6, dk = c & 63;
        C[(((size_t)(b * HH + h)) * TT + t) * DKK + dk] = v;
      } else {
        C[(size_t)r * DD + c] = v;
      }
    }
  }
}

// ---------------------------------------------------------------------------
// Flash attention, fp32.  Per block: 64 q-rows of one (b,h); 64-key tiles.
// 256 threads; thread (tx,ty) owns score/O rows {ty+16i}, score cols {tx+16j},
// O cols {tx*4+jj}.  Online softmax; P staged via LDS.
// ---------------------------------------------------------------------------
__global__ __launch_bounds__(256) void attn_f32(
    const float* __restrict__ Q, const float* __restrict__ K,
    const float* __restrict__ V, const int* __restrict__ mask,
    float* __restrict__ Ab) {
  const int bh = blockIdx.y;  // 0..63
  const int b = bh >> 4;
  const int h = bh & 15;
  const int qbase = blockIdx.x * 64;
  const float* Qp = Q + (size_t)bh * TT * DKK;
  const float* Kp = K + (size_t)bh * TT * DKK;
  const float* Vp = V + (size_t)bh * TT * DKK;
  const int* mp = mask + b * TT;

  __shared__ float Qs[64][68];
  __shared__ float Ks[64][68];
  __shared__ float Vs[64][68];
  __shared__ float Ps[64][68];

  const int tid = threadIdx.x;
  const int tx = tid & 15, ty = tid >> 4;

  {  // load Q tile 64x64
    const int r = tid >> 2, c = (tid & 3) * 16;
    const float4* g =
        reinterpret_cast<const float4*>(&Qp[(size_t)(qbase + r) * DKK + c]);
    *reinterpret_cast<float4*>(&Qs[r][c]) = g[0];
    *reinterpret_cast<float4*>(&Qs[r][c + 4]) = g[1];
    *reinterpret_cast<float4*>(&Qs[r][c + 8]) = g[2];
    *reinterpret_cast<float4*>(&Qs[r][c + 12]) = g[3];
  }

  float o[4][4];
#pragma unroll
  for (int i = 0; i < 4; ++i)
#pragma unroll
    for (int j = 0; j < 4; ++j) o[i][j] = 0.f;
  float m_[4] = {-INFINITY, -INFINITY, -INFINITY, -INFINITY};
  float l_[4] = {0.f, 0.f, 0.f, 0.f};

  for (int k0 = 0; k0 < TT; k0 += 64) {
    __syncthreads();  // prev tile's LDS reads done
    {
      const int r = tid >> 2, c = (tid & 3) * 16;
      const float4* kg =
          reinterpret_cast<const float4*>(&Kp[(size_t)(k0 + r) * DKK + c]);
      *reinterpret_cast<float4*>(&Ks[r][c]) = kg[0];
      *reinterpret_cast<float4*>(&Ks[r][c + 4]) = kg[1];
      *reinterpret_cast<float4*>(&Ks[r][c + 8]) = kg[2];
      *reinterpret_cast<float4*>(&Ks[r][c + 12]) = kg[3];
      const float4* vg =
          reinterpret_cast<const float4*>(&Vp[(size_t)(k0 + r) * DKK + c]);
      *reinterpret_cast<float4*>(&Vs[r][c]) = vg[0];
      *reinterpret_cast<float4*>(&Vs[r][c + 4]) = vg[1];
      *reinterpret_cast<float4*>(&Vs[r][c + 8]) = vg[2];
      *reinterpret_cast<float4*>(&Vs[r][c + 12]) = vg[3];
    }
    __syncthreads();

    // ---- scores S = (Q K^T)/8, mask ----
    float s[4][4];
#pragma unroll
    for (int i = 0; i < 4; ++i)
#pragma unroll
      for (int j = 0; j < 4; ++j) s[i][j] = 0.f;
#pragma unroll
    for (int d = 0; d < DKK; d += 4) {
      float4 qv[4], kv[4];
#pragma unroll
      for (int i = 0; i < 4; ++i)
        qv[i] = *reinterpret_cast<const float4*>(&Qs[ty + 16 * i][d]);
#pragma unroll
      for (int j = 0; j < 4; ++j)
        kv[j] = *reinterpret_cast<const float4*>(&Ks[tx + 16 * j][d]);
#pragma unroll
      for (int i = 0; i < 4; ++i)
#pragma unroll
        for (int j = 0; j < 4; ++j) {
          s[i][j] = fmaf(qv[i].x, kv[j].x, s[i][j]);
          s[i][j] = fmaf(qv[i].y, kv[j].y, s[i][j]);
          s[i][j] = fmaf(qv[i].z, kv[j].z, s[i][j]);
          s[i][j] = fmaf(qv[i].w, kv[j].w, s[i][j]);
        }
    }
    int mk[4];
#pragma unroll
    for (int j = 0; j < 4; ++j) mk[j] = mp[k0 + tx + 16 * j];
#pragma unroll
    for (int i = 0; i < 4; ++i)
#pragma unroll
      for (int j = 0; j < 4; ++j)
        s[i][j] = mk[j] ? s[i][j] * 0.125f : -1.0e9f;

    // ---- online softmax (row groups = 16 lanes sharing ty) ----
#pragma unroll
    for (int i = 0; i < 4; ++i) {
      float tm = fmaxf(fmaxf(s[i][0], s[i][1]), fmaxf(s[i][2], s[i][3]));
      tm = fmaxf(tm, __shfl_xor(tm, 1));
      tm = fmaxf(tm, __shfl_xor(tm, 2));
      tm = fmaxf(tm, __shfl_xor(tm, 4));
      tm = fmaxf(tm, __shfl_xor(tm, 8));
      const float nm = fmaxf(m_[i], tm);
      const float fac = __expf(m_[i] - nm);
      float rs = 0.f;
#pragma unroll
      for (int j = 0; j < 4; ++j) {
        s[i][j] = __expf(s[i][j] - nm);
        rs += s[i][j];
      }
      rs += __shfl_xor(rs, 1);
      rs += __shfl_xor(rs, 2);
      rs += __shfl_xor(rs, 4);
      rs += __shfl_xor(rs, 8);
      l_[i] = l_[i] * fac + rs;
      m_[i] = nm;
#pragma unroll
      for (int j = 0; j < 4; ++j) o[i][j] *= fac;
#pragma unroll
      for (int j = 0; j < 4; ++j) Ps[ty + 16 * i][tx + 16 * j] = s[i][j];
    }
    __syncthreads();  // P visible to all waves

    // ---- O += P @ V ----
#pragma unroll
    for (int kc = 0; kc < 64; kc += 4) {
      float4 pa[4], vb[4];
#pragma unroll
      for (int i = 0; i < 4; ++i)
        pa[i] = *reinterpret_cast<const float4*>(&Ps[ty + 16 * i][kc]);
#pragma unroll
      for (int k = 0; k < 4; ++k)
        vb[k] = *reinterpret_cast<const float4*>(&Vs[kc + k][tx * 4]);
#pragma unroll
      for (int i = 0; i < 4; ++i) {
        o[i][0] = fmaf(pa[i].x, vb[0].x, o[i][0]);
        o[i][0] = fmaf(pa[i].y, vb[1].x, o[i][0]);
        o[i][0] = fmaf(pa[i].z, vb[2].x, o[i][0]);
        o[i][0] = fmaf(pa[i].w, vb[3].x, o[i][0]);
        o[i][1] = fmaf(pa[i].x, vb[0].y, o[i][1]);
        o[i][1] = fmaf(pa[i].y, vb[1].y, o[i][1]);
        o[i][1] = fmaf(pa[i].z, vb[2].y, o[i][1]);
        o[i][1] = fmaf(pa[i].w, vb[3].y, o[i][1]);
        o[i][2] = fmaf(pa[i].x, vb[0].z, o[i][2]);
        o[i][2] = fmaf(pa[i].y, vb[1].z, o[i][2]);
        o[i][2] = fmaf(pa[i].z, vb[2].z, o[i][2]);
        o[i][2] = fmaf(pa[i].w, vb[3].z, o[i][2]);
        o[i][3] = fmaf(pa[i].x, vb[0].w, o[i][3]);
        o[i][3] = fmaf(pa[i].y, vb[1].w, o[i][3]);
        o[i][3] = fmaf(pa[i].z, vb[2].w, o[i][3]);
        o[i][3] = fmaf(pa[i].w, vb[3].w, o[i][3]);
      }
    }
  }

  // epilogue: write attn-out in (B,T,D) layout for the out-projection GEMM
#pragma unroll
  for (int i = 0; i < 4; ++i) {
    const float inv = 1.0f / l_[i];
    float4 r;
    r.x = o[i][0] * inv;
    r.y = o[i][1] * inv;
    r.z = o[i][2] * inv;
    r.w = o[i][3] * inv;
    const size_t idx =
        ((size_t)(b * TT + qbase + ty + 16 * i)) * DD + h * DKK + tx * 4;
    *reinterpret_cast<float4*>(&Ab[idx]) = r;
  }
}

extern "C" void kernel_launch(void* const* d_in, const int* in_sizes, int n_in,
                              void* d_out, int out_size, void* d_ws,
                              size_t ws_size, hipStream_t stream) {
  const float* x = (const float*)d_in[0];
  const int* attn_mask = (const int*)d_in[1];
  const float* wq = (const float*)d_in[2];
  const float* bq = (const float*)d_in[3];
  const float* wk = (const float*)d_in[4];
  const float* bk = (const float*)d_in[5];
  const float* wv = (const float*)d_in[6];
  const float* bv = (const float*)d_in[7];
  const float* wo = (const float*)d_in[8];
  const float* bo = (const float*)d_in[9];
  float* out = (float*)d_out;

  float* Qb = (float*)d_ws;                    // (B,H,T,DK)
  float* Kb = Qb + (size_t)NN * DD;
  float* Vb = Kb + (size_t)NN * DD;
  float* Ab = Vb + (size_t)NN * DD;            // (B,T,D)

  const dim3 gg(NN / 128, DD / 128);
  gemm_bias_f32<0><<<gg, 256, 0, stream>>>(x, wq, bq, Qb);
  gemm_bias_f32<0><<<gg, 256, 0, stream>>>(x, wk, bk, Kb);
  gemm_bias_f32<0><<<gg, 256, 0, stream>>>(x, wv, bv, Vb);
  attn_f32<<<dim3(TT / 64, BBATCH * HH), 256, 0, stream>>>(Qb, Kb, Vb,
                                                           attn_mask, Ab);
  gemm_bias_f32<1><<<gg, 256, 0, stream>>>(Ab, wo, bo, out);
}

// Round 2
// 347.766 us; speedup vs baseline: 9.8593x; 9.8593x over previous
//
#include <hip/hip_runtime.h>
#include <math.h>

#define TT 2048
#define DD 1024
#define HH 16
#define DKK 64
#define BB 4
#define NN 8192  // BB*TT

typedef __bf16 bf16x8 __attribute__((ext_vector_type(8)));
typedef float f32x4 __attribute__((ext_vector_type(4)));

// round-to-nearest-even f32 -> bf16 bits
__device__ __forceinline__ unsigned short f2bf(float f) {
  unsigned int u = __builtin_bit_cast(unsigned int, f);
  u += 0x7fffu + ((u >> 16) & 1u);
  return (unsigned short)(u >> 16);
}

__device__ __forceinline__ void gl_lds16(const void* g, void* s) {
  __builtin_amdgcn_global_load_lds(
      (const __attribute__((address_space(1))) void*)g,
      (__attribute__((address_space(3))) void*)s, 16, 0, 0);
}

// XOR swizzle within a 128B row: spreads 16-lane row-column reads across banks
#define SWZ(r, byte) ((byte) ^ (((r) & 7) << 4))

// ---------------------------------------------------------------------------
__global__ __launch_bounds__(256) void cast_f32_bf16(
    const float* __restrict__ in, unsigned short* __restrict__ out, int n4) {
  int i = blockIdx.x * blockDim.x + threadIdx.x;
  if (i < n4) {
    float4 v = reinterpret_cast<const float4*>(in)[i];
    ushort4 o;
    o.x = f2bf(v.x); o.y = f2bf(v.y); o.z = f2bf(v.z); o.w = f2bf(v.w);
    reinterpret_cast<ushort4*>(out)[i] = o;
  }
}

// transpose + cast 4 weights (DDxDD f32 row-major [k][n]) -> WT bf16 [n][k]
__global__ __launch_bounds__(256) void wtrans(
    const float* __restrict__ W0, const float* __restrict__ W1,
    const float* __restrict__ W2, const float* __restrict__ W3,
    unsigned short* __restrict__ WT) {
  __shared__ float t[32][33];
  const float* W = (blockIdx.z == 0) ? W0
                   : (blockIdx.z == 1) ? W1
                   : (blockIdx.z == 2) ? W2 : W3;
  unsigned short* O = WT + (size_t)blockIdx.z * DD * DD;
  const int tx = threadIdx.x & 31, ty = threadIdx.x >> 5;
  const int r0 = blockIdx.y * 32, c0 = blockIdx.x * 32;
#pragma unroll
  for (int j = 0; j < 4; ++j)
    t[ty + 8 * j][tx] = W[(size_t)(r0 + ty + 8 * j) * DD + c0 + tx];
  __syncthreads();
#pragma unroll
  for (int j = 0; j < 4; ++j)
    O[(size_t)(c0 + ty + 8 * j) * DD + r0 + tx] = f2bf(t[tx][ty + 8 * j]);
}

// ---------------------------------------------------------------------------
// C = A(bf16 Mx1024) @ WT^T + bias.  WT: [N][K] bf16 (B^T form).
// m97 structure: 128x128 tile, BK=32, 4 waves (2x2 of 64x64), linear LDS,
// global_load_lds width-16, 2 barriers per K-step.
// MODE 0: bf16 scatter (B,H,T,DK); MODE 1: bf16 scatter (B,H,DK,T);
// MODE 2: f32 row-major.
template <int MODE>
__global__ __launch_bounds__(256) void gemm_bf16(
    const unsigned short* __restrict__ A, const unsigned short* __restrict__ Bw,
    const float* __restrict__ bias, void* __restrict__ Cout) {
  __shared__ unsigned short As[128 * 32];
  __shared__ unsigned short Bs[128 * 32];
  const int tid = threadIdx.x;
  const int l = tid & 63, w = tid >> 6;
  const int ln = l & 15, kg = l >> 4;
  const int wr = w >> 1, wc = w & 1;
  const int rb = blockIdx.x * 128, cb = blockIdx.y * 128;

  f32x4 acc[4][4];
#pragma unroll
  for (int i = 0; i < 4; ++i)
#pragma unroll
    for (int j = 0; j < 4; ++j)
#pragma unroll
      for (int r = 0; r < 4; ++r) acc[i][j][r] = 0.f;

  // staging: tile rows 64B; wave w issue j covers LDS [j*4096 + w*1024, +1024)
  const int srow = w * 16 + (l >> 2);  // row for issue 0
  const int sch = (l & 3) * 16;        // byte within 64B row
  const char* Ag = (const char*)A + (size_t)(rb + srow) * 2048 + sch;
  const char* Bg = (const char*)Bw + (size_t)(cb + srow) * 2048 + sch;
  char* Ad = (char*)As + w * 1024;
  char* Bd = (char*)Bs + w * 1024;

  for (int k0 = 0; k0 < 2048; k0 += 64) {  // k0 in bytes (32 bf16)
    __syncthreads();
    gl_lds16(Ag + k0, Ad);
    gl_lds16(Ag + k0 + (size_t)64 * 2048, Ad + 4096);
    gl_lds16(Bg + k0, Bd);
    gl_lds16(Bg + k0 + (size_t)64 * 2048, Bd + 4096);
    __syncthreads();
    bf16x8 af[4], bfv[4];
#pragma unroll
    for (int mi = 0; mi < 4; ++mi)
      af[mi] = *reinterpret_cast<const bf16x8*>(
          (const char*)As + (wr * 64 + mi * 16 + ln) * 64 + kg * 16);
#pragma unroll
    for (int ni = 0; ni < 4; ++ni)
      bfv[ni] = *reinterpret_cast<const bf16x8*>(
          (const char*)Bs + (wc * 64 + ni * 16 + ln) * 64 + kg * 16);
#pragma unroll
    for (int mi = 0; mi < 4; ++mi)
#pragma unroll
      for (int ni = 0; ni < 4; ++ni)
        acc[mi][ni] = __builtin_amdgcn_mfma_f32_16x16x32_bf16(
            af[mi], bfv[ni], acc[mi][ni], 0, 0, 0);
  }

#pragma unroll
  for (int ni = 0; ni < 4; ++ni) {
    const int cl = cb + wc * 64 + ni * 16 + ln;
    const float bsv = bias[cl];
#pragma unroll
    for (int mi = 0; mi < 4; ++mi) {
#pragma unroll
      for (int r = 0; r < 4; ++r) {
        const int rl = rb + wr * 64 + mi * 16 + kg * 4 + r;
        const float v = acc[mi][ni][r] + bsv;
        if (MODE == 0) {
          const int b = rl >> 11, t = rl & 2047, h = cl >> 6, dk = cl & 63;
          ((unsigned short*)
               Cout)[(((size_t)(b * HH + h)) * TT + t) * DKK + dk] = f2bf(v);
        } else if (MODE == 1) {
          const int b = rl >> 11, t = rl & 2047, h = cl >> 6, dk = cl & 63;
          ((unsigned short*)
               Cout)[(((size_t)(b * HH + h)) * DKK + dk) * TT + t] = f2bf(v);
        } else {
          ((float*)Cout)[(size_t)rl * DD + cl] = v;
        }
      }
    }
  }
}

// ---------------------------------------------------------------------------
// Flash attention, bf16 MFMA.  Block: 128 q-rows of one (b,h); 4 waves own
// 32 q-rows each (2 m-frags).  KV tiles of 64.  Q hoisted to regs; K and V^T
// staged via global_load_lds with XOR-swizzled source; P reuses Q's LDS
// (wave-private rows -> no extra barrier).  Softmax fp32 in C-frag layout.
__global__ __launch_bounds__(256) void attn_mfma(
    const unsigned short* __restrict__ Qb, const unsigned short* __restrict__ Kb,
    const unsigned short* __restrict__ Vt, const int* __restrict__ mask,
    unsigned short* __restrict__ Ab) {
  const int bh = blockIdx.y, b = bh >> 4, h = bh & 15;
  const int qbase = blockIdx.x * 128;
  const char* Qp = (const char*)(Qb + (size_t)bh * TT * DKK);
  const char* Kp = (const char*)(Kb + (size_t)bh * TT * DKK);
  const char* Vp = (const char*)(Vt + (size_t)bh * DKK * TT);
  const int* mp = mask + b * TT;

  __shared__ char qp[16384];   // Q then P: [128 rows][128B], swizzled
  __shared__ char kbuf[8192];  // [64][128B] swizzled
  __shared__ char vbuf[8192];  // [64 d-rows][128B] swizzled (V^T)

  const int tid = threadIdx.x;
  const int l = tid & 63, w = tid >> 6;
  const int ln = l & 15, kg = l >> 4;

  // staging geometry: 128B tile rows; wave issue covers 8 rows
  const int srow = w * 8 + (l >> 3);        // row for issue 0
  const int sch = (l & 7) * 16;
  const int ssw = SWZ(srow, sch);           // (row+32k) keeps (row&7)

  {  // stage Q: 16KB = 4 issues/wave
    const char* src = Qp + ((size_t)(qbase + srow) << 7) + ssw;
    char* dst = qp + w * 1024;
#pragma unroll
    for (int j = 0; j < 4; ++j)
      gl_lds16(src + (size_t)j * 32 * 128, dst + j * 4096);
  }
  __syncthreads();

  bf16x8 qf[2][2];
#pragma unroll
  for (int mi = 0; mi < 2; ++mi)
#pragma unroll
    for (int ks = 0; ks < 2; ++ks) {
      const int row = w * 32 + mi * 16 + ln;
      qf[mi][ks] = *reinterpret_cast<const bf16x8*>(
          qp + row * 128 + SWZ(row, ks * 64 + kg * 16));
    }

  f32x4 out[2][4];
#pragma unroll
  for (int mi = 0; mi < 2; ++mi)
#pragma unroll
    for (int nd = 0; nd < 4; ++nd)
#pragma unroll
      for (int r = 0; r < 4; ++r) out[mi][nd][r] = 0.f;
  float m_[2][4], l_[2][4];
#pragma unroll
  for (int mi = 0; mi < 2; ++mi)
#pragma unroll
    for (int r = 0; r < 4; ++r) { m_[mi][r] = -INFINITY; l_[mi][r] = 0.f; }

  for (int kt = 0; kt < TT; kt += 64) {
    __syncthreads();  // all waves done reading kbuf/vbuf of prev tile
    {
      const char* ks_ = Kp + ((size_t)(kt + srow) << 7) + ssw;
      gl_lds16(ks_, kbuf + w * 1024);
      gl_lds16(ks_ + 32 * 128, kbuf + w * 1024 + 4096);
      const char* vs_ = Vp + (size_t)srow * (TT * 2) + (size_t)kt * 2 + ssw;
      gl_lds16(vs_, vbuf + w * 1024);
      gl_lds16(vs_ + (size_t)32 * (TT * 2), vbuf + w * 1024 + 4096);
    }
    __syncthreads();

    // ---- S = Q K^T ----
    f32x4 s[2][4];
#pragma unroll
    for (int mi = 0; mi < 2; ++mi)
#pragma unroll
      for (int ni = 0; ni < 4; ++ni)
#pragma unroll
        for (int r = 0; r < 4; ++r) s[mi][ni][r] = 0.f;
#pragma unroll
    for (int ks = 0; ks < 2; ++ks) {
      bf16x8 kf[4];
#pragma unroll
      for (int ni = 0; ni < 4; ++ni) {
        const int row = ni * 16 + ln;
        kf[ni] = *reinterpret_cast<const bf16x8*>(
            kbuf + row * 128 + SWZ(row, ks * 64 + kg * 16));
      }
#pragma unroll
      for (int mi = 0; mi < 2; ++mi)
#pragma unroll
        for (int ni = 0; ni < 4; ++ni)
          s[mi][ni] = __builtin_amdgcn_mfma_f32_16x16x32_bf16(
              qf[mi][ks], kf[ni], s[mi][ni], 0, 0, 0);
    }

    int mk[4];
#pragma unroll
    for (int ni = 0; ni < 4; ++ni) mk[ni] = mp[kt + ni * 16 + ln];

    // ---- online softmax (per lane: rows kg*4+r of each m-frag) ----
#pragma unroll
    for (int mi = 0; mi < 2; ++mi) {
#pragma unroll
      for (int r = 0; r < 4; ++r) {
        float sv0 = mk[0] ? s[mi][0][r] * 0.125f : -1.0e9f;
        float sv1 = mk[1] ? s[mi][1][r] * 0.125f : -1.0e9f;
        float sv2 = mk[2] ? s[mi][2][r] * 0.125f : -1.0e9f;
        float sv3 = mk[3] ? s[mi][3][r] * 0.125f : -1.0e9f;
        float tm = fmaxf(fmaxf(sv0, sv1), fmaxf(sv2, sv3));
        tm = fmaxf(tm, __shfl_xor(tm, 1));
        tm = fmaxf(tm, __shfl_xor(tm, 2));
        tm = fmaxf(tm, __shfl_xor(tm, 4));
        tm = fmaxf(tm, __shfl_xor(tm, 8));
        const float nm = fmaxf(m_[mi][r], tm);
        const float fac = __expf(m_[mi][r] - nm);
        m_[mi][r] = nm;
        const float p0 = __expf(sv0 - nm);
        const float p1 = __expf(sv1 - nm);
        const float p2 = __expf(sv2 - nm);
        const float p3 = __expf(sv3 - nm);
        float rs = p0 + p1 + p2 + p3;
        rs += __shfl_xor(rs, 1);
        rs += __shfl_xor(rs, 2);
        rs += __shfl_xor(rs, 4);
        rs += __shfl_xor(rs, 8);
        l_[mi][r] = l_[mi][r] * fac + rs;
#pragma unroll
        for (int nd = 0; nd < 4; ++nd) out[mi][nd][r] *= fac;
        const int qrow = w * 32 + mi * 16 + kg * 4 + r;
        char* prow = qp + qrow * 128;
        *(unsigned short*)(prow + SWZ(qrow, (0 * 16 + ln) * 2)) = f2bf(p0);
        *(unsigned short*)(prow + SWZ(qrow, (1 * 16 + ln) * 2)) = f2bf(p1);
        *(unsigned short*)(prow + SWZ(qrow, (2 * 16 + ln) * 2)) = f2bf(p2);
        *(unsigned short*)(prow + SWZ(qrow, (3 * 16 + ln) * 2)) = f2bf(p3);
      }
    }

    // ---- O += P @ V  (P rows are wave-private; lgkmcnt ordering suffices) --
#pragma unroll
    for (int ks = 0; ks < 2; ++ks) {
      bf16x8 pf[2], vf[4];
#pragma unroll
      for (int mi = 0; mi < 2; ++mi) {
        const int row = w * 32 + mi * 16 + ln;
        pf[mi] = *reinterpret_cast<const bf16x8*>(
            qp + row * 128 + SWZ(row, ks * 64 + kg * 16));
      }
#pragma unroll
      for (int nd = 0; nd < 4; ++nd) {
        const int row = nd * 16 + ln;
        vf[nd] = *reinterpret_cast<const bf16x8*>(
            vbuf + row * 128 + SWZ(row, ks * 64 + kg * 16));
      }
#pragma unroll
      for (int mi = 0; mi < 2; ++mi)
#pragma unroll
        for (int nd = 0; nd < 4; ++nd)
          out[mi][nd] = __builtin_amdgcn_mfma_f32_16x16x32_bf16(
              pf[mi], vf[nd], out[mi][nd], 0, 0, 0);
    }
  }

  // epilogue: Ab (B,T,D) bf16
#pragma unroll
  for (int mi = 0; mi < 2; ++mi) {
#pragma unroll
    for (int r = 0; r < 4; ++r) {
      const float inv = 1.0f / l_[mi][r];
      const int t = qbase + w * 32 + mi * 16 + kg * 4 + r;
#pragma unroll
      for (int nd = 0; nd < 4; ++nd) {
        const int c = h * DKK + nd * 16 + ln;
        Ab[((size_t)(b * TT + t)) * DD + c] = f2bf(out[mi][nd][r] * inv);
      }
    }
  }
}

// ---------------------------------------------------------------------------
extern "C" void kernel_launch(void* const* d_in, const int* in_sizes, int n_in,
                              void* d_out, int out_size, void* d_ws,
                              size_t ws_size, hipStream_t stream) {
  const float* x = (const float*)d_in[0];
  const int* attn_mask = (const int*)d_in[1];
  const float* wq = (const float*)d_in[2];
  const float* bq = (const float*)d_in[3];
  const float* wk = (const float*)d_in[4];
  const float* bk = (const float*)d_in[5];
  const float* wv = (const float*)d_in[6];
  const float* bv = (const float*)d_in[7];
  const float* wo = (const float*)d_in[8];
  const float* bo = (const float*)d_in[9];
  float* out = (float*)d_out;

  unsigned short* Xb = (unsigned short*)d_ws;          // NN*DD
  unsigned short* WT = Xb + (size_t)NN * DD;           // 4*DD*DD
  unsigned short* Qw = WT + (size_t)4 * DD * DD;       // NN*DD (B,H,T,DK)
  unsigned short* Kw = Qw + (size_t)NN * DD;           // NN*DD (B,H,T,DK)
  unsigned short* Vw = Kw + (size_t)NN * DD;           // NN*DD (B,H,DK,T)
  unsigned short* Ab = Vw + (size_t)NN * DD;           // NN*DD (B,T,D)

  cast_f32_bf16<<<(NN * DD / 4 + 255) / 256, 256, 0, stream>>>(
      x, Xb, NN * DD / 4);
  wtrans<<<dim3(DD / 32, DD / 32, 4), 256, 0, stream>>>(wq, wk, wv, wo, WT);

  const dim3 gg(NN / 128, DD / 128);
  gemm_bf16<0><<<gg, 256, 0, stream>>>(Xb, WT, bq, Qw);
  gemm_bf16<0><<<gg, 256, 0, stream>>>(Xb, WT + (size_t)DD * DD, bk, Kw);
  gemm_bf16<1><<<gg, 256, 0, stream>>>(Xb, WT + (size_t)2 * DD * DD, bv, Vw);
  attn_mfma<<<dim3(TT / 128, BB * HH), 256, 0, stream>>>(Qw, Kw, Vw, attn_mask,
                                                         Ab);
  gemm_bf16<2><<<gg, 256, 0, stream>>>(Ab, WT + (size_t)3 * DD * DD, bo, out);
}

// Round 3
// 248.111 us; speedup vs baseline: 13.8193x; 1.4017x over previous
//
#include <hip/hip_runtime.h>
#include <math.h>

#define TT 2048
#define DD 1024
#define HH 16
#define DKK 64
#define BB 4
#define NN 8192  // BB*TT

typedef __bf16 bf16x8 __attribute__((ext_vector_type(8)));
typedef float f32x4 __attribute__((ext_vector_type(4)));
typedef float f32x16 __attribute__((ext_vector_type(16)));

// round-to-nearest-even f32 -> bf16 bits
__device__ __forceinline__ unsigned short f2bf(float f) {
  unsigned int u = __builtin_bit_cast(unsigned int, f);
  u += 0x7fffu + ((u >> 16) & 1u);
  return (unsigned short)(u >> 16);
}

// v_cvt_pk_bf16_f32: dst.lo16 = bf16(lo), dst.hi16 = bf16(hi)
__device__ __forceinline__ unsigned int cvtpk(float lo, float hi) {
  unsigned int r;
  asm("v_cvt_pk_bf16_f32 %0, %1, %2" : "=v"(r) : "v"(lo), "v"(hi));
  return r;
}

__device__ __forceinline__ void gl_lds16(const void* g, void* s) {
  __builtin_amdgcn_global_load_lds(
      (const __attribute__((address_space(1))) void*)g,
      (__attribute__((address_space(3))) void*)s, 16, 0, 0);
}

// XOR swizzle within a 128B row: spreads column reads across banks
#define SWZ(r, byte) ((byte) ^ (((r) & 7) << 4))

// ---------------------------------------------------------------------------
__global__ __launch_bounds__(256) void cast_f32_bf16(
    const float* __restrict__ in, unsigned short* __restrict__ out, int n4) {
  int i = blockIdx.x * blockDim.x + threadIdx.x;
  if (i < n4) {
    float4 v = reinterpret_cast<const float4*>(in)[i];
    ushort4 o;
    o.x = f2bf(v.x); o.y = f2bf(v.y); o.z = f2bf(v.z); o.w = f2bf(v.w);
    reinterpret_cast<ushort4*>(out)[i] = o;
  }
}

// transpose + cast 4 weights (DDxDD f32 row-major [k][n]) -> WT bf16 [n][k]
__global__ __launch_bounds__(256) void wtrans(
    const float* __restrict__ W0, const float* __restrict__ W1,
    const float* __restrict__ W2, const float* __restrict__ W3,
    unsigned short* __restrict__ WT) {
  __shared__ float t[32][33];
  const float* W = (blockIdx.z == 0) ? W0
                   : (blockIdx.z == 1) ? W1
                   : (blockIdx.z == 2) ? W2 : W3;
  unsigned short* O = WT + (size_t)blockIdx.z * DD * DD;
  const int tx = threadIdx.x & 31, ty = threadIdx.x >> 5;
  const int r0 = blockIdx.y * 32, c0 = blockIdx.x * 32;
#pragma unroll
  for (int j = 0; j < 4; ++j)
    t[ty + 8 * j][tx] = W[(size_t)(r0 + ty + 8 * j) * DD + c0 + tx];
  __syncthreads();
#pragma unroll
  for (int j = 0; j < 4; ++j)
    O[(size_t)(c0 + ty + 8 * j) * DD + r0 + tx] = f2bf(t[tx][ty + 8 * j]);
}

// ---------------------------------------------------------------------------
// C = (A @ WT^T + bias) * scale.  m97 structure (see round-2 notes).
// MODE 0: bf16 scatter (B,H,T,DK); MODE 1: bf16 scatter (B,H,DK,T);
// MODE 2: f32 row-major.
template <int MODE>
__global__ __launch_bounds__(256) void gemm_bf16(
    const unsigned short* __restrict__ A, const unsigned short* __restrict__ Bw,
    const float* __restrict__ bias, void* __restrict__ Cout, float scale) {
  __shared__ unsigned short As[128 * 32];
  __shared__ unsigned short Bs[128 * 32];
  const int tid = threadIdx.x;
  const int l = tid & 63, w = tid >> 6;
  const int ln = l & 15, kg = l >> 4;
  const int wr = w >> 1, wc = w & 1;
  const int rb = blockIdx.x * 128, cb = blockIdx.y * 128;

  f32x4 acc[4][4];
#pragma unroll
  for (int i = 0; i < 4; ++i)
#pragma unroll
    for (int j = 0; j < 4; ++j)
#pragma unroll
      for (int r = 0; r < 4; ++r) acc[i][j][r] = 0.f;

  const int srow = w * 16 + (l >> 2);
  const int sch = (l & 3) * 16;
  const char* Ag = (const char*)A + (size_t)(rb + srow) * 2048 + sch;
  const char* Bg = (const char*)Bw + (size_t)(cb + srow) * 2048 + sch;
  char* Ad = (char*)As + w * 1024;
  char* Bd = (char*)Bs + w * 1024;

  for (int k0 = 0; k0 < 2048; k0 += 64) {
    __syncthreads();
    gl_lds16(Ag + k0, Ad);
    gl_lds16(Ag + k0 + (size_t)64 * 2048, Ad + 4096);
    gl_lds16(Bg + k0, Bd);
    gl_lds16(Bg + k0 + (size_t)64 * 2048, Bd + 4096);
    __syncthreads();
    bf16x8 af[4], bfv[4];
#pragma unroll
    for (int mi = 0; mi < 4; ++mi)
      af[mi] = *reinterpret_cast<const bf16x8*>(
          (const char*)As + (wr * 64 + mi * 16 + ln) * 64 + kg * 16);
#pragma unroll
    for (int ni = 0; ni < 4; ++ni)
      bfv[ni] = *reinterpret_cast<const bf16x8*>(
          (const char*)Bs + (wc * 64 + ni * 16 + ln) * 64 + kg * 16);
#pragma unroll
    for (int mi = 0; mi < 4; ++mi)
#pragma unroll
      for (int ni = 0; ni < 4; ++ni)
        acc[mi][ni] = __builtin_amdgcn_mfma_f32_16x16x32_bf16(
            af[mi], bfv[ni], acc[mi][ni], 0, 0, 0);
  }

#pragma unroll
  for (int ni = 0; ni < 4; ++ni) {
    const int cl = cb + wc * 64 + ni * 16 + ln;
    const float bsv = bias[cl];
#pragma unroll
    for (int mi = 0; mi < 4; ++mi) {
#pragma unroll
      for (int r = 0; r < 4; ++r) {
        const int rl = rb + wr * 64 + mi * 16 + kg * 4 + r;
        const float v = (acc[mi][ni][r] + bsv) * scale;
        if (MODE == 0) {
          const int b = rl >> 11, t = rl & 2047, h = cl >> 6, dk = cl & 63;
          ((unsigned short*)
               Cout)[(((size_t)(b * HH + h)) * TT + t) * DKK + dk] = f2bf(v);
        } else if (MODE == 1) {
          const int b = rl >> 11, t = rl & 2047, h = cl >> 6, dk = cl & 63;
          ((unsigned short*)
               Cout)[(((size_t)(b * HH + h)) * DKK + dk) * TT + t] = f2bf(v);
        } else {
          ((float*)Cout)[(size_t)rl * DD + cl] = v;
        }
      }
    }
  }
}

// ---------------------------------------------------------------------------
// Flash attention, swapped 32x32 MFMA (m214 structure).
// Block: 4 waves x 32 q-rows = 128 q of one (b,h).  KV tiles of 64.
// S^T = mfma(K, Q^T): lane owns q = lane&31; its 32 P-values are lane-local
// (kv = 32c + (reg&3) + 8*(reg>>2) + 4*hi).  Softmax: local max/sum + one
// shfl_xor(32).  P -> bf16 B-frags via cvt_pk + word exchange (no LDS).
// O^T = mfma(V^T, P^T): O columns lane-local -> rescale lane-local.
// Mask = additive bias (-1e9) from LDS.  Defer-max THR=8.
__global__ __launch_bounds__(256) void attn_mfma2(
    const unsigned short* __restrict__ Qb, const unsigned short* __restrict__ Kb,
    const unsigned short* __restrict__ Vt, const int* __restrict__ mask,
    unsigned short* __restrict__ Ab) {
  const int bh = blockIdx.y, b = bh >> 4, h = bh & 15;
  const int qbase = blockIdx.x * 128;
  const char* Qp = (const char*)(Qb + (size_t)bh * TT * DKK);
  const char* Kp = (const char*)(Kb + (size_t)bh * TT * DKK);
  const char* Vp = (const char*)(Vt + (size_t)bh * DKK * TT);
  const int* mp = mask + b * TT;

  __shared__ char qlds[16384];   // Q stage, then O transpose buffer
  __shared__ char kbuf[8192];    // K tile [64 kv][128B], swizzled
  __shared__ char vbuf[8192];    // V^T tile [64 d][128B], swizzled
  __shared__ float mb[TT];       // mask bias 0 / -1e9

  const int tid = threadIdx.x;
  const int l = tid & 63, w = tid >> 6;
  const int ln = l & 31, hi = l >> 5;

  for (int i = tid; i < TT; i += 256) mb[i] = mp[i] ? 0.f : -1.0e9f;

  const int srow = w * 8 + (l >> 3);
  const int ssw = SWZ(srow, (l & 7) * 16);
  {  // stage Q: 128 rows x 128B
    const char* src = Qp + ((size_t)(qbase + srow) << 7) + ssw;
    char* dst = qlds + w * 1024;
#pragma unroll
    for (int j = 0; j < 4; ++j)
      gl_lds16(src + (size_t)j * 32 * 128, dst + j * 4096);
  }
  __syncthreads();

  bf16x8 qf[4];
  const int qrow = w * 32 + ln;
#pragma unroll
  for (int s = 0; s < 4; ++s)
    qf[s] = *reinterpret_cast<const bf16x8*>(
        qlds + qrow * 128 + SWZ(qrow, s * 32 + hi * 16));

  f32x16 oc0, oc1;
#pragma unroll
  for (int i = 0; i < 16; ++i) { oc0[i] = 0.f; oc1[i] = 0.f; }
  float m_ = -INFINITY, l_ = 0.f;

  for (int kt = 0; kt < TT; kt += 64) {
    __syncthreads();  // all waves done reading kbuf/vbuf of prev tile
    {
      const char* ksrc = Kp + ((size_t)(kt + srow) << 7) + ssw;
      gl_lds16(ksrc, kbuf + w * 1024);
      gl_lds16(ksrc + 32 * 128, kbuf + w * 1024 + 4096);
      const char* vsrc = Vp + (size_t)srow * 4096 + (size_t)kt * 2 + ssw;
      gl_lds16(vsrc, vbuf + w * 1024);
      gl_lds16(vsrc + (size_t)32 * 4096, vbuf + w * 1024 + 4096);
    }
    __syncthreads();

    // ---- S^T: two 32x32 chunks ----
    f32x16 sc0, sc1;
#pragma unroll
    for (int i = 0; i < 16; ++i) { sc0[i] = 0.f; sc1[i] = 0.f; }
#pragma unroll
    for (int s = 0; s < 4; ++s) {
      const bf16x8 kf0 = *reinterpret_cast<const bf16x8*>(
          kbuf + ln * 128 + SWZ(ln, s * 32 + hi * 16));
      const bf16x8 kf1 = *reinterpret_cast<const bf16x8*>(
          kbuf + (32 + ln) * 128 + SWZ(ln, s * 32 + hi * 16));
      sc0 = __builtin_amdgcn_mfma_f32_32x32x16_bf16(kf0, qf[s], sc0, 0, 0, 0);
      sc1 = __builtin_amdgcn_mfma_f32_32x32x16_bf16(kf1, qf[s], sc1, 0, 0, 0);
    }

    // ---- mask bias (additive) ----
#pragma unroll
    for (int g = 0; g < 4; ++g) {
      const float4 m0 = *reinterpret_cast<const float4*>(
          &mb[kt + 4 * hi + 8 * g]);
      const float4 m1 = *reinterpret_cast<const float4*>(
          &mb[kt + 32 + 4 * hi + 8 * g]);
      sc0[4 * g + 0] += m0.x; sc0[4 * g + 1] += m0.y;
      sc0[4 * g + 2] += m0.z; sc0[4 * g + 3] += m0.w;
      sc1[4 * g + 0] += m1.x; sc1[4 * g + 1] += m1.y;
      sc1[4 * g + 2] += m1.z; sc1[4 * g + 3] += m1.w;
    }

    // ---- online softmax: lane-local row + one cross-half reduce ----
    float tm = sc0[0];
#pragma unroll
    for (int i = 1; i < 16; ++i) tm = fmaxf(tm, sc0[i]);
#pragma unroll
    for (int i = 0; i < 16; ++i) tm = fmaxf(tm, sc1[i]);
    tm = fmaxf(tm, __shfl_xor(tm, 32));
    if (__any(tm - m_ > 8.f)) {  // defer-max (T13)
      const float nm = fmaxf(m_, tm);
      const float fac = __expf(m_ - nm);
      m_ = nm;
      l_ *= fac;
#pragma unroll
      for (int i = 0; i < 16; ++i) { oc0[i] *= fac; oc1[i] *= fac; }
    }
    float rs = 0.f;
#pragma unroll
    for (int i = 0; i < 16; ++i) { sc0[i] = __expf(sc0[i] - m_); rs += sc0[i]; }
#pragma unroll
    for (int i = 0; i < 16; ++i) { sc1[i] = __expf(sc1[i] - m_); rs += sc1[i]; }
    rs += __shfl_xor(rs, 32);
    l_ += rs;

    // ---- P -> bf16 B-frags (cvt_pk + half exchange, T12 pattern) ----
    bf16x8 pf[4];
#pragma unroll
    for (int s = 0; s < 4; ++s) {
      const int u = s & 1;
      float p0, p1, p2, p3, p4, p5, p6, p7;
      if ((s >> 1) == 0) {
        p0 = sc0[8 * u + 0]; p1 = sc0[8 * u + 1]; p2 = sc0[8 * u + 2];
        p3 = sc0[8 * u + 3]; p4 = sc0[8 * u + 4]; p5 = sc0[8 * u + 5];
        p6 = sc0[8 * u + 6]; p7 = sc0[8 * u + 7];
      } else {
        p0 = sc1[8 * u + 0]; p1 = sc1[8 * u + 1]; p2 = sc1[8 * u + 2];
        p3 = sc1[8 * u + 3]; p4 = sc1[8 * u + 4]; p5 = sc1[8 * u + 5];
        p6 = sc1[8 * u + 6]; p7 = sc1[8 * u + 7];
      }
      const unsigned int wa0 = cvtpk(p0, p1), wa1 = cvtpk(p2, p3);
      const unsigned int wb0 = cvtpk(p4, p5), wb1 = cvtpk(p6, p7);
      const unsigned int ea0 = (unsigned int)__shfl_xor((int)wa0, 32);
      const unsigned int ea1 = (unsigned int)__shfl_xor((int)wa1, 32);
      const unsigned int eb0 = (unsigned int)__shfl_xor((int)wb0, 32);
      const unsigned int eb1 = (unsigned int)__shfl_xor((int)wb1, 32);
      union { unsigned int u4[4]; bf16x8 v; } pw;
      pw.u4[0] = hi ? eb0 : wa0;
      pw.u4[1] = hi ? eb1 : wa1;
      pw.u4[2] = hi ? wb0 : ea0;
      pw.u4[3] = hi ? wb1 : ea1;
      pf[s] = pw.v;
    }

    // ---- O^T += V^T @ P^T ----
#pragma unroll
    for (int s = 0; s < 4; ++s) {
      const bf16x8 vf0 = *reinterpret_cast<const bf16x8*>(
          vbuf + ln * 128 + SWZ(ln, s * 32 + hi * 16));
      const bf16x8 vf1 = *reinterpret_cast<const bf16x8*>(
          vbuf + (32 + ln) * 128 + SWZ(ln, s * 32 + hi * 16));
      oc0 = __builtin_amdgcn_mfma_f32_32x32x16_bf16(vf0, pf[s], oc0, 0, 0, 0);
      oc1 = __builtin_amdgcn_mfma_f32_32x32x16_bf16(vf1, pf[s], oc1, 0, 0, 0);
    }
  }

  // ---- epilogue: normalize, transpose O through qlds, store (B,T,D) ----
  const float inv = 1.0f / l_;
#pragma unroll
  for (int i = 0; i < 16; ++i) { oc0[i] *= inv; oc1[i] *= inv; }
  // lane holds O^T[d][q=ln31]; write O rows [q][d] bf16 into qlds [128][128B]
#pragma unroll
  for (int g = 0; g < 4; ++g) {
    const int d0a = 8 * g + 4 * hi;           // oc0 d-base
    uint2 wv;
    wv.x = cvtpk(oc0[4 * g + 0], oc0[4 * g + 1]);
    wv.y = cvtpk(oc0[4 * g + 2], oc0[4 * g + 3]);
    *reinterpret_cast<uint2*>(qlds + qrow * 128 + SWZ(qrow, d0a * 2)) = wv;
    uint2 wv1;
    wv1.x = cvtpk(oc1[4 * g + 0], oc1[4 * g + 1]);
    wv1.y = cvtpk(oc1[4 * g + 2], oc1[4 * g + 3]);
    *reinterpret_cast<uint2*>(qlds + qrow * 128 + SWZ(qrow, 64 + d0a * 2)) =
        wv1;
  }
  __syncthreads();
  {
    const int row2 = tid >> 1, halfc = tid & 1;
    char* gout = (char*)Ab + ((size_t)(b * TT + qbase + row2)) * 2048 +
                 h * 128 + halfc * 64;
#pragma unroll
    for (int u2 = 0; u2 < 4; ++u2) {
      const uint4 d4 = *reinterpret_cast<const uint4*>(
          qlds + row2 * 128 + SWZ(row2, halfc * 64 + u2 * 16));
      *reinterpret_cast<uint4*>(gout + u2 * 16) = d4;
    }
  }
}

// ---------------------------------------------------------------------------
extern "C" void kernel_launch(void* const* d_in, const int* in_sizes, int n_in,
                              void* d_out, int out_size, void* d_ws,
                              size_t ws_size, hipStream_t stream) {
  const float* x = (const float*)d_in[0];
  const int* attn_mask = (const int*)d_in[1];
  const float* wq = (const float*)d_in[2];
  const float* bq = (const float*)d_in[3];
  const float* wk = (const float*)d_in[4];
  const float* bk = (const float*)d_in[5];
  const float* wv = (const float*)d_in[6];
  const float* bv = (const float*)d_in[7];
  const float* wo = (const float*)d_in[8];
  const float* bo = (const float*)d_in[9];
  float* out = (float*)d_out;

  unsigned short* Xb = (unsigned short*)d_ws;          // NN*DD
  unsigned short* WT = Xb + (size_t)NN * DD;           // 4*DD*DD
  unsigned short* Qw = WT + (size_t)4 * DD * DD;       // (B,H,T,DK), pre-scaled
  unsigned short* Kw = Qw + (size_t)NN * DD;           // (B,H,T,DK)
  unsigned short* Vw = Kw + (size_t)NN * DD;           // (B,H,DK,T)
  unsigned short* Ab = Vw + (size_t)NN * DD;           // (B,T,D)

  cast_f32_bf16<<<(NN * DD / 4 + 255) / 256, 256, 0, stream>>>(
      x, Xb, NN * DD / 4);
  wtrans<<<dim3(DD / 32, DD / 32, 4), 256, 0, stream>>>(wq, wk, wv, wo, WT);

  const dim3 gg(NN / 128, DD / 128);
  gemm_bf16<0><<<gg, 256, 0, stream>>>(Xb, WT, bq, Qw, 0.125f);
  gemm_bf16<0><<<gg, 256, 0, stream>>>(Xb, WT + (size_t)DD * DD, bk, Kw, 1.f);
  gemm_bf16<1><<<gg, 256, 0, stream>>>(Xb, WT + (size_t)2 * DD * DD, bv, Vw,
                                       1.f);
  attn_mfma2<<<dim3(TT / 128, BB * HH), 256, 0, stream>>>(Qw, Kw, Vw,
                                                          attn_mask, Ab);
  gemm_bf16<2><<<gg, 256, 0, stream>>>(Ab, WT + (size_t)3 * DD * DD, bo, out,
                                       1.f);
}